// Round 5
// baseline (473.724 us; speedup 1.0000x reference)
//
#include <hip/hip_runtime.h>
#include <math.h>

#define EPSV 1e-5f

typedef __attribute__((ext_vector_type(8))) short bf16x8;
typedef __attribute__((ext_vector_type(4))) float f32x4;
typedef unsigned short u16;

__device__ __forceinline__ u16 f2bf(float f) {
    unsigned int u = __float_as_uint(f);
    return (u16)((u + 0x7fffu + ((u >> 16) & 1u)) >> 16);
}
__device__ __forceinline__ float b2f(u16 u) {
    return __uint_as_float(((unsigned int)u) << 16);
}

__device__ __forceinline__ void glds16(const u16* g, u16* l) {
    __builtin_amdgcn_global_load_lds(
        (const __attribute__((address_space(1))) void*)g,
        (__attribute__((address_space(3))) void*)l, 16, 0, 0);
}

#define BARRIER() asm volatile("s_barrier" ::: "memory")
#define VMCNT(n)  asm volatile("s_waitcnt vmcnt(" #n ")" ::: "memory")

// ============ 128x256 triple-buffered bf16 MFMA GEMM (B^T) ==============
// C[M,N] = A[M,K] * B[N,K]^T (+bias). BM=128 BN=256 BK=64, 512 thr = 8 waves
// (2M x 4N), wave tile 64x64 (acc[4][4] of 16x16x32). LDS 144KB TRIPLE buffer,
// vmcnt(6) steady state. XOR-swizzled rows. XCD-aware (x,y) swizzle: each XCD
// gets a contiguous chunk of x-columns traversed y-fastest, so B-panel
// re-reads hit that XCD's private L2 (blocks stream k in near-lockstep ->
// live working set is a few k-slices).
// PVEPI: head = col>>9, A += head*aH, fused skip+aw*ew epilogue (fp32 out).
template<int BIAS, int OUTBF, int PVEPI>
__global__ __launch_bounds__(512, 2) void gemm256(
    const u16* __restrict__ A, const u16* __restrict__ B,
    const float* __restrict__ bias, void* __restrict__ Cout,
    int K, int lda, int ldb, int ldc, long aH, long bH, long cH,
    const u16* __restrict__ skipb, int ldsk,
    const float* __restrict__ aw, const float* __restrict__ ew, int H)
{
    __shared__ __align__(16) u16 LB[3 * 24576];   // 3 x (A 16KB | B 32KB)
    const int tid = threadIdx.x;
    const int wid = tid >> 6, lane = tid & 63;
    const int wm = wid >> 2, wn = wid & 3;
    const int fr = lane & 15, g = lane >> 4;

    // ---- XCD-aware block swizzle (bijective; gx*gy divisible by 8) ----
    const int gx = gridDim.x, gy = gridDim.y;
    const int lid = blockIdx.y * gx + blockIdx.x;
    const int mchunk = (gx * gy) >> 3;
    const int nl = (lid & 7) * mchunk + (lid >> 3);
    const int bxi = nl / gy, byi = nl % gy;      // y-fastest within chunk
    const int bm = byi * 128, bn = bxi * 256;

    if (PVEPI) { A += (long)(bn >> 9) * aH; }
    else       { A += (long)blockIdx.z * aH; B += (long)blockIdx.z * bH; }

    // staging addressing: thread -> row srow of 64-row chunk, k-chunk (tid&7)
    const int srow = tid >> 3;
    const int kx = ((tid & 7) ^ (srow & 7)) << 3;   // inverse-swizzled src k
    const u16* gA = A + (long)(bm + srow) * lda + kx;
    const u16* gB = B + (long)(bn + srow) * ldb + kx;

#define STAGEA(dst, tt) do { const u16* s_ = gA + ((long)(tt) << 6); \
    u16* d_ = (dst) + (wid << 9); \
    glds16(s_, d_); glds16(s_ + (long)64 * lda, d_ + 4096); } while (0)
#define STAGEB(dst, tt) do { const u16* s_ = gB + ((long)(tt) << 6); \
    u16* d_ = (dst) + 8192 + (wid << 9); \
    glds16(s_, d_); \
    glds16(s_ + (long)64 * ldb, d_ + 4096); \
    glds16(s_ + (long)128 * ldb, d_ + 8192); \
    glds16(s_ + (long)192 * ldb, d_ + 12288); } while (0)

    // fragment read addressing (swizzled)
    const int q0 = ((0 + g) ^ (fr & 7)) << 3;   // k-subtile 0
    const int q1 = ((4 + g) ^ (fr & 7)) << 3;   // k-subtile 1
    bf16x8 am[4], bq[4];
    f32x4 acc[4][4];
    #pragma unroll
    for (int m = 0; m < 4; m++)
        #pragma unroll
        for (int n = 0; n < 4; n++) acc[m][n] = (f32x4){0.f, 0.f, 0.f, 0.f};

#define RD8(bp, qq) do { \
    const u16* pa_ = (bp) + ((wm << 6) + fr) * 64; \
    const u16* pb_ = (bp) + 8192 + ((wn << 6) + fr) * 64; \
    am[0] = *(const bf16x8*)(pa_ + (qq)); \
    am[1] = *(const bf16x8*)(pa_ + 1024 + (qq)); \
    am[2] = *(const bf16x8*)(pa_ + 2048 + (qq)); \
    am[3] = *(const bf16x8*)(pa_ + 3072 + (qq)); \
    bq[0] = *(const bf16x8*)(pb_ + (qq)); \
    bq[1] = *(const bf16x8*)(pb_ + 1024 + (qq)); \
    bq[2] = *(const bf16x8*)(pb_ + 2048 + (qq)); \
    bq[3] = *(const bf16x8*)(pb_ + 3072 + (qq)); } while (0)

#define MFMA16() do { __builtin_amdgcn_s_setprio(1); \
    _Pragma("unroll") for (int m_ = 0; m_ < 4; m_++) \
    _Pragma("unroll") for (int n_ = 0; n_ < 4; n_++) \
        acc[m_][n_] = __builtin_amdgcn_mfma_f32_16x16x32_bf16(am[m_], bq[n_], acc[m_][n_], 0, 0, 0); \
    __builtin_amdgcn_s_setprio(0); } while (0)

    u16* pr = LB;                 // tile t
    u16* pn = LB + 24576;         // tile t+1
    u16* ps = LB + 49152;         // stage target (t+2)

    // prologue: tiles 0,1 staged; wait tile 0
    STAGEA(pr, 0); STAGEB(pr, 0);
    STAGEA(pn, 1); STAGEB(pn, 1);
    VMCNT(6);
    BARRIER();

    const int NT = K >> 6;
    for (int t = 0; t < NT - 2; ++t) {
        // ph1 (k-subtile 0)
        RD8(pr, q0);
        STAGEA(ps, t + 2);
        BARRIER();
        MFMA16();
        BARRIER();
        // ph2 (k-subtile 1)
        RD8(pr, q1);
        STAGEB(ps, t + 2);
        VMCNT(6);          // tile t+1 landed; tile t+2's 6 stay in flight
        BARRIER();
        MFMA16();
        BARRIER();
        u16* tmp = pr; pr = pn; pn = ps; ps = tmp;
    }
    // tile NT-2 (no staging)
    RD8(pr, q0); BARRIER(); MFMA16(); BARRIER();
    RD8(pr, q1);
    VMCNT(0);              // drain tile NT-1
    BARRIER();
    MFMA16();
    // tile NT-1 (all landed; no LDS writes remain -> no barriers)
    RD8(pn, q0); MFMA16();
    RD8(pn, q1); MFMA16();

    // ---- epilogue: C/D layout col=lane&15, row=(lane>>4)*4+j ----
    const int er = g << 2;
    const int crow0 = bm + (wm << 6);
    const int ccol0 = bn + (wn << 6);
    if (PVEPI) {
        float* C = (float*)Cout;
        #pragma unroll
        for (int m = 0; m < 4; m++)
            #pragma unroll
            for (int n = 0; n < 4; n++) {
                int f = ccol0 + (n << 4) + fr;
                int h = f >> 9;
                float ewf = ew[f];
                #pragma unroll
                for (int j = 0; j < 4; j++) {
                    int row = crow0 + (m << 4) + er + j;
                    C[(long)row * ldc + f] = acc[m][n][j]
                        + b2f(skipb[(long)row * ldsk + f])
                        + aw[row * H + h] * ewf;
                }
            }
    } else if (OUTBF) {
        u16* C = (u16*)Cout + (long)blockIdx.z * cH;
        #pragma unroll
        for (int m = 0; m < 4; m++)
            #pragma unroll
            for (int n = 0; n < 4; n++) {
                int col = ccol0 + (n << 4) + fr;
                float bv = BIAS ? bias[col] : 0.f;
                #pragma unroll
                for (int j = 0; j < 4; j++)
                    C[(long)(crow0 + (m << 4) + er + j) * ldc + col] = f2bf(acc[m][n][j] + bv);
            }
    } else {
        float* C = (float*)Cout + (long)blockIdx.z * cH;
        #pragma unroll
        for (int m = 0; m < 4; m++)
            #pragma unroll
            for (int n = 0; n < 4; n++) {
                int col = ccol0 + (n << 4) + fr;
                #pragma unroll
                for (int j = 0; j < 4; j++)
                    C[(long)(crow0 + (m << 4) + er + j) * ldc + col] = acc[m][n][j];
            }
    }
#undef STAGEA
#undef STAGEB
#undef RD8
#undef MFMA16
}

// ============================ conversions ===============================
// x -> xT (fp32) and xb (bf16) in one pass
__global__ void xprep(const float* __restrict__ in, float* __restrict__ outT,
                      u16* __restrict__ outB)
{
    __shared__ float t[32][33];
    int bx = blockIdx.x * 32, by = blockIdx.y * 32;
    #pragma unroll
    for (int i = 0; i < 32; i += 8) {
        float v = in[(long)(by + threadIdx.y + i) * 1024 + bx + threadIdx.x];
        t[threadIdx.y + i][threadIdx.x] = v;
        outB[(long)(by + threadIdx.y + i) * 1024 + bx + threadIdx.x] = f2bf(v);
    }
    __syncthreads();
    #pragma unroll
    for (int i = 0; i < 32; i += 8)
        outT[(long)(bx + threadIdx.y + i) * 1024 + by + threadIdx.x] = t[threadIdx.x][threadIdx.y + i];
}

// up to 4 weights fp32 [K][F] -> bf16 [F][K], batched over blockIdx.z
__global__ void wtrans4(const float* s0, const float* s1, const float* s2, const float* s3,
                        u16* __restrict__ dst, int ldsrc, int Kdim, long dstride)
{
    int which = blockIdx.z;
    const float* src = which == 0 ? s0 : which == 1 ? s1 : which == 2 ? s2 : s3;
    dst += (long)which * dstride;
    __shared__ float t[32][33];
    int f0 = blockIdx.x * 32, k0 = blockIdx.y * 32;
    int tx = threadIdx.x, ty = threadIdx.y;
    #pragma unroll
    for (int i = 0; i < 4; i++)
        t[ty + i * 8][tx] = src[(long)(k0 + ty + i * 8) * ldsrc + f0 + tx];
    __syncthreads();
    #pragma unroll
    for (int i = 0; i < 4; i++)
        dst[(long)(f0 + ty + i * 8) * Kdim + k0 + tx] = f2bf(t[tx][ty + i * 8]);
}

// V block (bf16, strided) -> VT per head: dst[h*512*1024 + d*1024 + r]
__global__ void transpose_b2b(const u16* __restrict__ src,
                              u16* __restrict__ dst, int ldsrc, int Cd)
{
    __shared__ u16 t[32][33];
    int h = blockIdx.z;
    int d0 = blockIdx.x * 32, r0 = blockIdx.y * 32;
    int tx = threadIdx.x, ty = threadIdx.y;
    #pragma unroll
    for (int i = 0; i < 4; i++)
        t[ty + i * 8][tx] = src[(long)(r0 + ty + i * 8) * ldsrc + h * Cd + d0 + tx];
    __syncthreads();
    #pragma unroll
    for (int i = 0; i < 4; i++)
        dst[(long)h * Cd * 1024 + (long)(d0 + ty + i * 8) * 1024 + r0 + tx] = t[tx][ty + i * 8];
}

__global__ void concat4(const float* __restrict__ a, const float* __restrict__ b,
                        const float* __restrict__ c, const float* __restrict__ d,
                        float* __restrict__ o, int F)
{
    int i = blockIdx.x * 256 + threadIdx.x;
    const float* s = (i < F) ? a : (i < 2 * F) ? b : (i < 3 * F) ? c : d;
    o[i] = s[i & (F - 1)];
}

// ================== softmax with fused qe + edge term ===================
__global__ __launch_bounds__(256) void softmax_qe(
    const float* __restrict__ S, const float* __restrict__ xT,
    const u16* __restrict__ qmat, int ldq, const float* __restrict__ ew,
    float* __restrict__ aw, u16* __restrict__ ab, int H, float isd)
{
    const int c = blockIdx.x, h = blockIdx.y, tid = threadIdx.x;
    __shared__ float red[8];
    // qe[c,h] = q[c, h*512: ] . ew[h*512: ]
    const u16* qr = qmat + (long)c * ldq + (h << 9);
    const float* wv = ew + (h << 9);
    int d = tid << 1;
    float p = b2f(qr[d]) * wv[d] + b2f(qr[d + 1]) * wv[d + 1];
    #pragma unroll
    for (int o = 32; o; o >>= 1) p += __shfl_xor(p, o);
    if ((tid & 63) == 0) red[tid >> 6] = p;
    __syncthreads();
    const float qeh = (red[0] + red[1] + red[2] + red[3]) * isd;
    __syncthreads();

    const float* row = S + ((long)h * 1024 + c) * 1024;
    u16* arow = ab + ((long)h * 1024 + c) * 1024;
    const float* xc = xT + (long)c * 1024;
    float l[4], xv[4];
    float mx = -1e30f;
    #pragma unroll
    for (int i = 0; i < 4; i++) {
        int r = tid + i * 256;
        xv[i] = xc[r];
        l[i] = row[r] * isd + xv[i] * qeh;
        mx = fmaxf(mx, l[i]);
    }
    #pragma unroll
    for (int o = 32; o; o >>= 1) mx = fmaxf(mx, __shfl_xor(mx, o));
    if ((tid & 63) == 0) red[tid >> 6] = mx;
    __syncthreads();
    mx = fmaxf(fmaxf(red[0], red[1]), fmaxf(red[2], red[3]));
    __syncthreads();
    float e[4], se = 0.f, sa = 0.f;
    #pragma unroll
    for (int i = 0; i < 4; i++) {
        e[i] = __expf(l[i] - mx);
        se += e[i];
        sa += e[i] * xv[i];
    }
    #pragma unroll
    for (int o = 32; o; o >>= 1) { se += __shfl_xor(se, o); sa += __shfl_xor(sa, o); }
    if ((tid & 63) == 0) { red[tid >> 6] = se; red[4 + (tid >> 6)] = sa; }
    __syncthreads();
    se = red[0] + red[1] + red[2] + red[3];
    sa = red[4] + red[5] + red[6] + red[7];
    float inv = 1.f / se;
    #pragma unroll
    for (int i = 0; i < 4; i++) arow[tid + i * 256] = f2bf(e[i] * inv);
    if (tid == 0) aw[c * H + h] = sa * inv;
}

// ============================ GraphNorm =================================
__global__ void col_stats1(const float* __restrict__ X, float* __restrict__ ps,
                           float* __restrict__ ps2, int F)
{
    int f = blockIdx.x * 256 + threadIdx.x;
    int r0 = blockIdx.y * 32;
    float s = 0.f, s2 = 0.f;
    for (int r = r0; r < r0 + 32; r++) {
        float v = X[(long)r * F + f];
        s += v; s2 += v * v;
    }
    ps [(long)blockIdx.y * F + f] = s;
    ps2[(long)blockIdx.y * F + f] = s2;
}

__global__ void col_stats2(const float* __restrict__ ps, const float* __restrict__ ps2,
    const float* __restrict__ ms, float* __restrict__ msmu, float* __restrict__ rs, int F)
{
    int f = blockIdx.x * 256 + threadIdx.x;
    float s = 0.f, s2 = 0.f;
    for (int ch = 0; ch < 32; ch++) { s += ps[(long)ch * F + f]; s2 += ps2[(long)ch * F + f]; }
    float m  = s  * (1.f / 1024.f);
    float m2 = s2 * (1.f / 1024.f);
    float a = ms[f] * m;
    msmu[f] = a;
    float var = m2 - 2.f * a * m + a * a;
    rs[f] = rsqrtf(var + EPSV);
}

// L1: apply GraphNorm, write bf16
__global__ void gnorm_apply_b(const float* __restrict__ X, u16* __restrict__ Yb,
    const float* __restrict__ msmu, const float* __restrict__ rs,
    const float* __restrict__ g, const float* __restrict__ b, int F)
{
    long idx = ((long)blockIdx.x * 256 + threadIdx.x) * 4;
    int f = (int)(idx % F);
    float4 v = *(const float4*)&X[idx];
    v.x = g[f+0] * (v.x - msmu[f+0]) * rs[f+0] + b[f+0];
    v.y = g[f+1] * (v.y - msmu[f+1]) * rs[f+1] + b[f+1];
    v.z = g[f+2] * (v.z - msmu[f+2]) * rs[f+2] + b[f+2];
    v.w = g[f+3] * (v.w - msmu[f+3]) * rs[f+3] + b[f+3];
    u16 o[4] = { f2bf(v.x), f2bf(v.y), f2bf(v.z), f2bf(v.w) };
    *(ushort4*)&Yb[idx] = *(ushort4*)o;
}

// L2 final: GraphNorm apply + row L2-normalize, one pass (F == 4096)
__global__ __launch_bounds__(256) void gnorm_l2(
    float* __restrict__ X, const float* __restrict__ msmu,
    const float* __restrict__ rs, const float* __restrict__ g,
    const float* __restrict__ b, int F)
{
    const int r = blockIdx.x, tid = threadIdx.x;
    float* row = X + (long)r * F;
    float v[16];
    float ss = 0.f;
    #pragma unroll
    for (int i = 0; i < 4; i++) {
        int f = (tid << 2) + (i << 10);
        float4 x4 = *(const float4*)&row[f];
        float a0 = g[f+0] * (x4.x - msmu[f+0]) * rs[f+0] + b[f+0];
        float a1 = g[f+1] * (x4.y - msmu[f+1]) * rs[f+1] + b[f+1];
        float a2 = g[f+2] * (x4.z - msmu[f+2]) * rs[f+2] + b[f+2];
        float a3 = g[f+3] * (x4.w - msmu[f+3]) * rs[f+3] + b[f+3];
        v[i*4+0] = a0; v[i*4+1] = a1; v[i*4+2] = a2; v[i*4+3] = a3;
        ss += a0*a0 + a1*a1 + a2*a2 + a3*a3;
    }
    __shared__ float red[4];
    #pragma unroll
    for (int o = 32; o; o >>= 1) ss += __shfl_xor(ss, o);
    if ((tid & 63) == 0) red[tid >> 6] = ss;
    __syncthreads();
    ss = red[0] + red[1] + red[2] + red[3];
    float inv = rsqrtf(ss);
    #pragma unroll
    for (int i = 0; i < 4; i++) {
        int f = (tid << 2) + (i << 10);
        float4 o4;
        o4.x = v[i*4+0] * inv; o4.y = v[i*4+1] * inv;
        o4.z = v[i*4+2] * inv; o4.w = v[i*4+3] * inv;
        *(float4*)&row[f] = o4;
    }
}

// ============================ host side =================================
static inline void g256_proj(hipStream_t st, const u16* A, const u16* B, const float* bias,
                             u16* C, int M, int N, int K, int lda, int ldb, int ldc)
{
    dim3 gr(N / 256, M / 128, 1), bl(512);
    gemm256<1,1,0><<<gr, bl, 0, st>>>(A, B, bias, C, K, lda, ldb, ldc, 0, 0, 0,
                                      nullptr, 0, nullptr, nullptr, 0);
}
static inline void g256_qk(hipStream_t st, const u16* A, const u16* B, float* C,
                           int K, int lda, int ldb, int H)
{
    dim3 gr(1024 / 256, 1024 / 128, H), bl(512);
    gemm256<0,0,0><<<gr, bl, 0, st>>>(A, B, nullptr, C, K, lda, ldb, 1024,
                                      512, 512, (long)1024 * 1024,
                                      nullptr, 0, nullptr, nullptr, 0);
}
static inline void g256_pv(hipStream_t st, const u16* A, const u16* B, float* C,
                           int H, int F, const u16* skipb, int ldsk,
                           const float* aw, const float* ew)
{
    dim3 gr((H * 512) / 256, 1024 / 128, 1), bl(512);
    gemm256<0,0,1><<<gr, bl, 0, st>>>(A, B, nullptr, C, 1024, 1024, 1024, F,
                                      (long)1024 * 1024, 0, 0,
                                      skipb, ldsk, aw, ew, H);
}

extern "C" void kernel_launch(void* const* d_in, const int* in_sizes, int n_in,
                              void* d_out, int out_size, void* d_ws, size_t ws_size,
                              hipStream_t stream)
{
    const float* x    = (const float*)d_in[0];
    const float* q1w  = (const float*)d_in[1];  const float* q1b = (const float*)d_in[2];
    const float* k1w  = (const float*)d_in[3];  const float* k1b = (const float*)d_in[4];
    const float* v1w  = (const float*)d_in[5];  const float* v1b = (const float*)d_in[6];
    const float* e1w  = (const float*)d_in[7];
    const float* s1w  = (const float*)d_in[8];  const float* s1b = (const float*)d_in[9];
    const float* gn1g = (const float*)d_in[10]; const float* gn1b = (const float*)d_in[11];
    const float* gn1ms= (const float*)d_in[12];
    const float* q2w  = (const float*)d_in[13]; const float* q2b = (const float*)d_in[14];
    const float* k2w  = (const float*)d_in[15]; const float* k2b = (const float*)d_in[16];
    const float* v2w  = (const float*)d_in[17]; const float* v2b = (const float*)d_in[18];
    const float* e2w  = (const float*)d_in[19];
    const float* s2w  = (const float*)d_in[20]; const float* s2b = (const float*)d_in[21];
    const float* gn2g = (const float*)d_in[22]; const float* gn2b = (const float*)d_in[23];
    const float* gn2ms= (const float*)d_in[24];
    float* out = (float*)d_out;

    // workspace layout; peak ~107 MB
    char* W = (char*)d_ws;
    float* xT    = (float*)W;               W += (long)1024 * 1024 * 4;      // 4 MB
    u16*   xb    = (u16*)W;                 W += (long)1024 * 1024 * 2;      // 2 MB
    float* h1    = (float*)W;               W += (long)1024 * 2048 * 4;      // 8 MB
    u16*   h1b   = (u16*)W;                 W += (long)1024 * 2048 * 2;      // 4 MB
    u16*   projC = (u16*)W;                 W += (long)1024 * 16384 * 2;     // 32 MB
    char*  R     = W;                       W += (long)8192 * 2048 * 2;      // 32 MB (WT | S alias)
    u16*   WT    = (u16*)R;
    float* S     = (float*)R;
    u16*   ab    = (u16*)W;                 W += (long)8 * 1024 * 1024 * 2;  // 16 MB
    u16*   VT    = (u16*)W;                 W += (long)8 * 512 * 1024 * 2;   // 8 MB
    float* bc    = (float*)W;               W += 16384 * 4;
    float* aw    = (float*)W;               W += 8192 * 4;
    float* ps    = (float*)W;               W += (long)32 * 4096 * 4;
    float* ps2   = (float*)W;               W += (long)32 * 4096 * 4;
    float* msmu  = (float*)W;               W += 4096 * 4;
    float* rs    = (float*)W;               W += 4096 * 4;

    const float isd = 1.0f / sqrtf(512.0f);

    xprep<<<dim3(32, 32), dim3(32, 8), 0, stream>>>(x, xT, xb);

    // ---------------- Layer 1: H=4, Cd=512, Fin=1024, F=2048 ----------------
    {
        const int F = 2048, K = 1024, H = 4;
        wtrans4<<<dim3(64, 32, 4), dim3(32, 8), 0, stream>>>(
            q1w, k1w, v1w, s1w, WT, F, K, (long)F * K);
        concat4<<<32, 256, 0, stream>>>(q1b, k1b, v1b, s1b, bc, F);
        // fused projection: [1024, 8192] bf16 (q|k|v|skip)
        g256_proj(stream, xb, WT, bc, projC, 1024, 4 * F, K, K, K, 4 * F);
        // QK^T per head -> S fp32 (overwrites WT; WT dead)
        g256_qk(stream, projC, projC + F, S, 512, 4 * F, 4 * F, H);
        softmax_qe<<<dim3(1024, H), 256, 0, stream>>>(S, xT, projC, 4 * F, e1w, aw, ab, H, isd);
        transpose_b2b<<<dim3(16, 32, H), dim3(32, 8), 0, stream>>>(projC + 2 * F, VT, 4 * F, 512);
        // PV (all heads, one launch) + fused skip+edge epilogue -> h1 fp32
        g256_pv(stream, ab, VT, h1, H, F, projC + 3 * F, 4 * F, aw, e1w);

        col_stats1<<<dim3(F / 256, 32), 256, 0, stream>>>(h1, ps, ps2, F);
        col_stats2<<<F / 256, 256, 0, stream>>>(ps, ps2, gn1ms, msmu, rs, F);
        gnorm_apply_b<<<(int)((long)1024 * F / 4 / 256), 256, 0, stream>>>(
            h1, h1b, msmu, rs, gn1g, gn1b, F);
    }

    // ---------------- Layer 2: H=8, Cd=512, Fin=2048, F=4096 ----------------
    {
        const int F = 4096, K = 2048, H = 8;
        concat4<<<64, 256, 0, stream>>>(q2b, k2b, v2b, s2b, bc, F);
        wtrans4<<<dim3(128, 64, 2), dim3(32, 8), 0, stream>>>(
            q2w, k2w, nullptr, nullptr, WT, F, K, (long)F * K);
        g256_proj(stream, h1b, WT, bc, projC, 1024, 2 * F, K, K, K, 4 * F);
        wtrans4<<<dim3(128, 64, 2), dim3(32, 8), 0, stream>>>(
            v2w, s2w, nullptr, nullptr, WT, F, K, (long)F * K);
        g256_proj(stream, h1b, WT, bc + 2 * F, projC + 2 * F, 1024, 2 * F, K, K, K, 4 * F);

        g256_qk(stream, projC, projC + F, S, 512, 4 * F, 4 * F, H);
        softmax_qe<<<dim3(1024, H), 256, 0, stream>>>(S, xT, projC, 4 * F, e2w, aw, ab, H, isd);
        transpose_b2b<<<dim3(16, 32, H), dim3(32, 8), 0, stream>>>(projC + 2 * F, VT, 4 * F, 512);
        g256_pv(stream, ab, VT, out, H, F, projC + 3 * F, 4 * F, aw, e2w);

        col_stats1<<<dim3(F / 256, 32), 256, 0, stream>>>(out, ps, ps2, F);
        col_stats2<<<F / 256, 256, 0, stream>>>(ps, ps2, gn2ms, msmu, rs, F);
        gnorm_l2<<<1024, 256, 0, stream>>>(out, msmu, rs, gn2g, gn2b, F);
    }
}